// Round 1
// 138.562 us; speedup vs baseline: 1.0099x; 1.0099x over previous
//
#include <hip/hip_runtime.h>
#include <hip/hip_bf16.h>
#include <stdint.h>

typedef __attribute__((ext_vector_type(8))) short short8;
typedef __attribute__((ext_vector_type(4))) float f32x4;

// ---------------- ws layout (bytes) ----------------
// Xpad granules: [b(8)][cb(8)][y(66)][x(66)][gslot(4)] * 16B = 17,842,176
#define XP_BYTES   17842176
#define XP_PAD     1024
#define OFF_W9     (XP_BYTES + XP_PAD)            // 17,843,200
#define W9_BYTES   (8*9*256*32*2)                 // 1,179,648
#define OFF_BIAS   (OFF_W9 + W9_BYTES)

__device__ __forceinline__ short f2bf(float f) {
  __hip_bfloat16 h = __float2bfloat16(f);
  return *reinterpret_cast<short*>(&h);
}

__device__ __forceinline__ void gl_lds16(const void* g, void* l) {
  __builtin_amdgcn_global_load_lds(
      (const __attribute__((address_space(1))) void*)g,
      (__attribute__((address_space(3))) void*)l, 16, 0, 0);
}

// Fused weight prep: H2 slice in LDS -> Wfull rows in regs -> W9 taps + bias.
// One block per o (256 blocks), one thread per c (256 threads).
__global__ void k_weights(const float* __restrict__ core1,
                          const float* __restrict__ core2,
                          const float* __restrict__ core3,
                          const float* __restrict__ convw,
                          const float* __restrict__ convb,
                          short* __restrict__ W9, float* __restrict__ bias) {
  __shared__ float H2s[1024];   // [u(16)][j(8)][k(8)]
  __shared__ float red[256];
  const int o = blockIdx.x, c = threadIdx.x;
  const int a = o >> 6, c2 = (o >> 3) & 7, d = o & 7;
  // phase 1: H2[c2,d,u,j,k] = sum_v G2[c2,v,u,j]*G3[d,v,k]
#pragma unroll
  for (int p = 0; p < 4; ++p) {
    int idx = c + (p << 8);
    int k = idx & 7, j = (idx >> 3) & 7, u = idx >> 6;
    float s = 0.f;
#pragma unroll
    for (int v = 0; v < 16; ++v)
      s += core2[(c2 * 16 + v) * 128 + u * 8 + j] * core3[d * 128 + v * 8 + k];
    H2s[idx] = s;
  }
  __syncthreads();
  // phase 2: Wr[r] = Wfull[o,c,r] = sum_u G1[a,u,r,i]*H2s[u,j,k]
  const int i = c >> 6, j = (c >> 3) & 7, k = c & 7;
  float Wr[16];
#pragma unroll
  for (int r = 0; r < 16; ++r) Wr[r] = 0.f;
  for (int u = 0; u < 16; ++u) {
    float h = H2s[u * 64 + j * 8 + k];
    const float* c1 = core1 + (a * 16 + u) * 64 + i;
#pragma unroll
    for (int r = 0; r < 16; ++r) Wr[r] += c1[r * 4] * h;
  }
  // phase 3a: 9 conv taps, swizzled W9 layout [cb][t][o][gslot][8]
  const int cb = c >> 5, cl = c & 31, g = cl >> 3, pos = cl & 7;
  const int gslot = g ^ (o & 3);
#pragma unroll
  for (int t = 0; t < 9; ++t) {
    float s = 0.f;
#pragma unroll
    for (int r = 0; r < 16; ++r) s += Wr[r] * convw[r * 9 + t];
    W9[((size_t)((cb * 9 + t) * 256 + o)) * 32 + gslot * 8 + pos] = f2bf(s);
  }
  // phase 3b: bias[o] = sum_{c,r} Wfull[o,c,r]*convb[r]
  float s = 0.f;
#pragma unroll
  for (int r = 0; r < 16; ++r) s += Wr[r] * convb[r];
  red[c] = s;
  __syncthreads();
  for (int st = 128; st > 0; st >>= 1) {
    if (c < st) red[c] += red[c + st];
    __syncthreads();
  }
  if (c == 0) bias[o] = red[0];
}

// pad+transpose: X (B,256,64,64) fp32 -> Xpad bf16 granules, INCLUDING zero
// borders (no memset needed). Grid x = padded row yp (0..65).
__global__ void k_pad(const float* __restrict__ X, short* __restrict__ Xp) {
  const int yp = blockIdx.x, b = blockIdx.y, cb = blockIdx.z;
  const int t = threadIdx.x;
  const int x = t & 63, sub = t >> 6;       // sub = channel-group g (0..3)
  const size_t rowg = ((size_t)((b * 8 + cb) * 66 + yp)) * 264; // 66*4 granules/row
  const short8 z = (short8){0, 0, 0, 0, 0, 0, 0, 0};
  if (yp == 0 || yp == 65) {
    // full zero row: xp = x (0..63) plus xp = 64+x for x<2
    *(short8*)(Xp + (rowg + (size_t)(x << 2) + sub) * 8) = z;
    if (x < 2)
      *(short8*)(Xp + (rowg + (size_t)((64 + x) << 2) + sub) * 8) = z;
    return;
  }
  const int y = yp - 1, xp = x + 1;
  const int gslot = sub ^ (xp & 3);
  const float* src = X + ((size_t)(b * 256 + cb * 32 + sub * 8) * 64 + y) * 64 + x;
  short8 v;
#pragma unroll
  for (int k = 0; k < 8; ++k) v[k] = f2bf(src[(size_t)k * 4096]);
  *(short8*)(Xp + (rowg + (size_t)(xp << 2) + gslot) * 8) = v;
  // left/right border columns (xp = 0 and 65), all 4 gslots via sub
  if (x < 2)
    *(short8*)(Xp + (rowg + (size_t)((x * 65) << 2) + sub) * 8) = z;
}

// stage one (cb) K-slab: X tile (10 padded rows, 42 chunks of 1 KB) + W tile
// (9 taps x 64 o x 32 c, 36 chunks). Issue-only; caller's barrier drains.
__device__ __forceinline__ void stage_tiles(
    const short* __restrict__ Xp, const short* __restrict__ W9,
    short* XLd, short* WLd, int cb, int h0, int oBase, int b, int wv, int lane) {
  const size_t xb = ((size_t)(((b << 3) + cb) * 66 + h0) * 66) << 5;
#pragma unroll 1
  for (int q = wv; q < 42; q += 4)
    gl_lds16(Xp + xb + (q << 9) + (lane << 3), XLd + (q << 9));
#pragma unroll 1
  for (int q = wv; q < 36; q += 4) {
    const int t = q >> 2, sub = q & 3;
    const short* g = W9 +
        (((size_t)(((cb * 9 + t) << 8) + oBase + (sub << 4))) << 5) + (lane << 3);
    gl_lds16(g, WLd + (((t << 6) + (sub << 4)) << 5));
  }
}

// main GEMM: out[b,o,h,w] = bias[o] + sum_{c,t} K9[o,c,t]*Xpad[b,c,h+dy,w+dx]
// 8 output rows / block, 2 rows / wave (af reused across rows, bfr across dy),
// full LDS double-buffer, one barrier per cb, prefetch issued before compute.
__global__ __launch_bounds__(256, 1) void k_gemm(
    const short* __restrict__ Xp, const short* __restrict__ W9,
    const float* __restrict__ bias, float* __restrict__ out) {
  __shared__ __align__(16) short XL[2][21504];   // 2 x 43,008 B (42 chunks)
  __shared__ __align__(16) short WL[2][18432];   // 2 x 36,864 B -> 159,744 B total

  const int tid  = threadIdx.x;
  const int lane = tid & 63;
  const int wv   = tid >> 6;           // 4 waves
  const int l15  = lane & 15;
  const int gl   = lane >> 4;          // k-granule 0..3
  const int h0    = blockIdx.x << 3;   // 8 output rows / block
  const int oBase = blockIdx.y << 6;   // 64 out-channels / block
  const int b     = blockIdx.z;
  const int r0    = wv << 1;           // this wave's local output-row base

  f32x4 acc[2][4][4];
#pragma unroll
  for (int rr = 0; rr < 2; ++rr)
#pragma unroll
    for (int io = 0; io < 4; ++io)
#pragma unroll
      for (int ip = 0; ip < 4; ++ip)
        acc[rr][io][ip] = (f32x4){0.f, 0.f, 0.f, 0.f};

  // prologue: stage cb=0 into buffer 0
  stage_tiles(Xp, W9, &XL[0][0], &WL[0][0], 0, h0, oBase, b, wv, lane);

  int cur = 0;
  for (int cb = 0; cb < 8; ++cb) {
    __syncthreads();                   // drains vmcnt(0): buf[cur] ready
    if (cb < 7)
      stage_tiles(Xp, W9, &XL[cur ^ 1][0], &WL[cur ^ 1][0],
                  cb + 1, h0, oBase, b, wv, lane);
    const short* XLc = &XL[cur][0];
    const short* WLc = &WL[cur][0];
#pragma unroll
    for (int dx = 0; dx < 3; ++dx) {
      // X fragments for 4 consecutive padded rows (serve dy x {row0,row1})
      short8 bfr[4][4];
#pragma unroll
      for (int xr = 0; xr < 4; ++xr) {
        const int prow = r0 + xr;
#pragma unroll
        for (int ip = 0; ip < 4; ++ip) {
          const int x = (ip << 4) + l15 + dx;
          bfr[xr][ip] = *(const short8*)&XLc[(((prow * 66 + x) << 2) + (gl ^ (x & 3))) << 3];
        }
      }
#pragma unroll
      for (int dy = 0; dy < 3; ++dy) {
        const int t = dy * 3 + dx;
        short8 af[4];
#pragma unroll
        for (int io = 0; io < 4; ++io) {
          const int ol = (io << 4) + l15;
          af[io] = *(const short8*)&WLc[(((t << 6) + ol) << 5) + ((gl ^ (ol & 3)) << 3)];
        }
#pragma unroll
        for (int io = 0; io < 4; ++io)
#pragma unroll
          for (int ip = 0; ip < 4; ++ip) {
            acc[0][io][ip] = __builtin_amdgcn_mfma_f32_16x16x32_bf16(
                af[io], bfr[dy][ip], acc[0][io][ip], 0, 0, 0);
            acc[1][io][ip] = __builtin_amdgcn_mfma_f32_16x16x32_bf16(
                af[io], bfr[dy + 1][ip], acc[1][io][ip], 0, 0, 0);
          }
      }
    }
    cur ^= 1;
  }

  // epilogue
#pragma unroll
  for (int rr = 0; rr < 2; ++rr) {
    const int h = h0 + r0 + rr;
#pragma unroll
    for (int io = 0; io < 4; ++io) {
#pragma unroll
      for (int r = 0; r < 4; ++r) {
        const int oG = oBase + (io << 4) + (gl << 2) + r;
        const float bv = bias[oG];
        float* op = out + (((size_t)((b << 8) + oG)) << 12) + (h << 6);
#pragma unroll
        for (int ip = 0; ip < 4; ++ip)
          op[(ip << 4) + l15] = acc[rr][io][ip][r] + bv;
      }
    }
  }
}

extern "C" void kernel_launch(void* const* d_in, const int* in_sizes, int n_in,
                              void* d_out, int out_size, void* d_ws, size_t ws_size,
                              hipStream_t stream) {
  (void)in_sizes; (void)n_in; (void)out_size; (void)ws_size;
  const float* X     = (const float*)d_in[0];
  const float* convw = (const float*)d_in[1];
  const float* convb = (const float*)d_in[2];
  const float* core1 = (const float*)d_in[3];
  const float* core2 = (const float*)d_in[4];
  const float* core3 = (const float*)d_in[5];
  float* out = (float*)d_out;
  char*  ws  = (char*)d_ws;

  short* Xp   = (short*)ws;
  short* W9   = (short*)(ws + OFF_W9);
  float* bias = (float*)(ws + OFF_BIAS);

  // no memset: k_pad writes every Xpad granule (borders = zero granules)
  k_weights<<<256, 256, 0, stream>>>(core1, core2, core3, convw, convb, W9, bias);
  k_pad    <<<dim3(66, 8, 8), 256, 0, stream>>>(X, Xp);
  k_gemm   <<<dim3(8, 4, 8), 256, 0, stream>>>(Xp, W9, bias, out);
}